// Round 6
// baseline (226.346 us; speedup 1.0000x reference)
//
#include <hip/hip_runtime.h>
#include <stdint.h>

// XGBoost forest inference: B=50000, F=256, T=1000, depth=6, 127 nodes/tree.
// v6: all-LDS walk (v1's proven 91cy/visit model) minus its three taxes:
//  - levels 0-2 cached in VGPRs (wave-uniform tops, prefetched one tile
//    ahead via BROADCAST global_load_dwordx4 -> vmcnt pipe, off-chain;
//    selection by cndmask on VALU which has 4x-per-SIMD headroom).
//    NO scalar loads in the walk (v3 lesson: smem poisons lgkmcnt FIFO).
//    NO divergent VMEM in the walk (v2/v4/v5 lesson: ~100cy/visit TA tax).
//  - mid levels 3-5 + leaf staged by global_load_lds from packed d_ws
//    arrays, double-buffered, 1 barrier/tile. Level 5 stored as split
//    f[32]/c[32] b32 arrays (conflict-free); lvl3/4 int2 b64 (<=16 distinct
//    addrs -> conflict-free); leaf b32 (2-way, cheap).
//  - forest padded to 1024 trees (zero dummies) -> all tiles 64 trees,
//    NSPLIT=2 + atomicAdd -> 1564 blocks, makespan x1.15 not x1.31.
// LDS/visit ~72cy -> ~110us model.

#define NFEAT   256
#define NNODES  127
#define NTREES  1000
#define TPAD    1024
#define SPB     64       // samples per block (= lanes per wave)
#define NTH     512      // 8 waves
#define TLANES  8
#define TILE_T  64       // trees per tile
#define MID_DW  112      // dwords per tree: lvl3 8*int2, lvl4 16*int2, lvl5 f[32]+c[32]
#define MID_B   448
#define NTILES  8        // 512 trees per block
#define TSPLIT  512
#define NSPLIT  2

#define TOP_OFF  0                          // int4[TPAD][4]   = 64 KB
#define LEAF_OFF (TPAD * 64)                // float[TPAD][64] = 256 KB
#define MID_OFF  (LEAF_OFF + TPAD * 256)    // int[TPAD][112]  = 448 KB
#define WS_NEED  (MID_OFF + TPAD * MID_B)   // 768 KB

typedef __attribute__((address_space(1))) const unsigned char ga_u8;
typedef __attribute__((address_space(3))) unsigned char       la_u8;

struct Top { int4 a, b, c, d; };  // (f0,c0,f1,c1)(f2,c2,f3,c3)(f4,c4,f5,c5)(f6,c6,-,-)

__global__ void xgb_init_kernel(const float* __restrict__ base_score,
                                float* __restrict__ out, int B)
{
    const int i = blockIdx.x * 256 + threadIdx.x;
    if (i < B) out[i] = base_score[0];
}

// pack tree data into d_ws; trees >= NTREES are zero dummies.
__global__ void xgb_pack_kernel(const int* __restrict__ idx,
                                const float* __restrict__ cond,
                                char* __restrict__ ws)
{
    const int i = blockIdx.x * 256 + threadIdx.x;
    if (i >= TPAD * NNODES) return;
    const int t  = i / NNODES;
    const int nd = i - t * NNODES;
    int   f = 0;
    float c = 0.0f;
    if (t < NTREES) { f = idx[i]; c = cond[i]; }

    if (nd < 7) {
        int* top = (int*)(ws + TOP_OFF) + t * 16;
        top[nd * 2]     = f;
        top[nd * 2 + 1] = __float_as_int(c);
        if (nd == 0) { top[14] = 0; top[15] = 0; }      // pad dwords
    } else if (nd < 31) {
        // lvl3 (7..14) + lvl4 (15..30): int2 at dw = 2*nd - 14
        int* mid = (int*)(ws + MID_OFF) + (size_t)t * MID_DW;
        mid[2 * nd - 14] = f;
        mid[2 * nd - 13] = __float_as_int(c);
    } else if (nd < 63) {
        // lvl5 (31..62): split arrays f at 48+q, c at 80+q
        int* mid = (int*)(ws + MID_OFF) + (size_t)t * MID_DW;
        const int q = nd - 31;
        mid[48 + q] = f;
        mid[80 + q] = __float_as_int(c);
    } else {
        ((float*)(ws + LEAF_OFF))[t * 64 + (nd - 63)] = c;
    }
}

// stage one 64-tree tile (mid 28KB + leaf 16KB) into LDS via global_load_lds.
// chunk index c is wave-uniform; global src per-lane (+lane*16); LDS dest =
// uniform base (+implicit lane*16) -- linear layouts on both sides.
__device__ __forceinline__ void stage_tile(const char* __restrict__ midG,
                                           const char* __restrict__ leafG,
                                           int treeBase, char* midDst,
                                           char* leafDst, int wid, int lane)
{
    for (int c = wid; c < 44; c += TLANES) {
        const char* g;
        char*       l;
        if (c < 28) {
            g = midG + (size_t)treeBase * MID_B + c * 1024;
            l = midDst + c * 1024;
        } else {
            g = leafG + (size_t)treeBase * 256 + (c - 28) * 1024;
            l = leafDst + (c - 28) * 1024;
        }
#if __has_builtin(__builtin_amdgcn_global_load_lds)
        __builtin_amdgcn_global_load_lds((ga_u8*)(uintptr_t)(g + lane * 16),
                                         (la_u8*)(uintptr_t)l, 16, 0, 0);
#else
        *reinterpret_cast<int4*>(l + lane * 16) =
            *reinterpret_cast<const int4*>(g + lane * 16);
#endif
    }
}

__global__ __launch_bounds__(NTH, 1) void xgb_forest_kernel(
    const float* __restrict__ x,
    const char*  __restrict__ ws,
    float* __restrict__ out, int B)
{
    __shared__ float xT[NFEAT * SPB];                        // 64 KB
    __shared__ __align__(16) int   midL[2][TILE_T * MID_DW]; // 56 KB
    __shared__ __align__(16) float leafL[2][TILE_T * 64];    // 32 KB
    __shared__ float partials[TLANES * SPB];                 //  2 KB

    const int4* top4  = (const int4*)(ws + TOP_OFF);
    const char* leafG = ws + LEAF_OFF;
    const char* midG  = ws + MID_OFF;

    const int tid   = threadIdx.x;
    const int sbase = (blockIdx.x >> 1) * SPB;
    const int t0    = (blockIdx.x & 1) * TSPLIT;
    const int s     = tid & 63;
    const int wid   = tid >> 6;

    // stage tile 0 (flies under x-staging)
    stage_tile(midG, leafG, t0, (char*)midL[0], (char*)leafL[0], wid, s);

    // preload tops for tile 0 (broadcast VMEM: all lanes same address)
    Top tv[8];
#pragma unroll
    for (int j = 0; j < 8; ++j) {
        const int tr = (t0 + wid + 8 * j) & (TPAD - 1);
        const int4* tp = top4 + tr * 4;
        tv[j].a = tp[0]; tv[j].b = tp[1]; tv[j].c = tp[2]; tv[j].d = tp[3];
    }

    // ---- stage x tile, transposed (gather bank = sample%32, conflict-free)
    {
        const int sq = tid & 15;
        const int cg = tid >> 4;               // 0..31
        for (int rg = 0; rg < 4; ++rg) {
            const int  sl = rg * 16 + sq;
            const bool ok = (sbase + sl) < B;
            for (int ci = 0; ci < 2; ++ci) {
                const int c4 = ci * 32 + cg;
                float4 v = make_float4(0.f, 0.f, 0.f, 0.f);
                if (ok)
                    v = *reinterpret_cast<const float4*>(
                        &x[(size_t)(sbase + sl) * NFEAT + c4 * 4]);
                xT[(c4 * 4 + 0) * SPB + sl] = v.x;
                xT[(c4 * 4 + 1) * SPB + sl] = v.y;
                xT[(c4 * 4 + 2) * SPB + sl] = v.z;
                xT[(c4 * 4 + 3) * SPB + sl] = v.w;
            }
        }
    }
    __syncthreads();   // xT + tile 0 (vmcnt drained) ready

    const float* xs = &xT[s];
    float acc = 0.0f;

    for (int t = 0; t < NTILES; ++t) {
        if (t + 1 < NTILES)
            stage_tile(midG, leafG, t0 + (t + 1) * TILE_T,
                       (char*)midL[(t + 1) & 1], (char*)leafL[(t + 1) & 1],
                       wid, s);

        const int*   mbuf = midL[t & 1];
        const float* lbuf = leafL[t & 1];
        int node[8];

        // ---- phase A: levels 0-2 from registers (VALU selects + LDS gathers)
#pragma unroll
        for (int j = 0; j < 8; ++j) {
            const int4 A = tv[j].a, Bq = tv[j].b, Cq = tv[j].c, Dq = tv[j].d;
            const float xv0 = xs[A.x * SPB];
            const bool  b0  = (xv0 - __int_as_float(A.y)) > 0.0f;
            const int   f1  = b0 ? Bq.x : A.z;
            const float c1  = __int_as_float(b0 ? Bq.y : A.w);
            const bool  b1  = (xs[f1 * SPB] - c1) > 0.0f;
            const int   f2  = b0 ? (b1 ? Dq.x : Cq.z) : (b1 ? Cq.x : Bq.z);
            const float c2  = __int_as_float(b0 ? (b1 ? Dq.y : Cq.w)
                                                : (b1 ? Cq.y : Bq.w));
            const bool  b2  = (xs[f2 * SPB] - c2) > 0.0f;
            node[j] = 7 + 4 * (int)b0 + 2 * (int)b1 + (int)b2;
            // prefetch next tile's top into tv[j] (WAR: after last use)
            const int tr = (t0 + (t + 1) * TILE_T + wid + 8 * j) & (TPAD - 1);
            const int4* tp = top4 + tr * 4;
            tv[j].a = tp[0]; tv[j].b = tp[1]; tv[j].c = tp[2]; tv[j].d = tp[3];
        }

        // ---- phase B: levels 3-5 + leaf from LDS tile
#pragma unroll
        for (int j = 0; j < 8; ++j) {          // level 3: node in 7..14
            const int lb = (wid + 8 * j) * MID_DW;
            const int2 nd = *reinterpret_cast<const int2*>(
                &mbuf[lb + 2 * node[j] - 14]);
            node[j] = 2 * node[j] + 1 +
                      (int)((xs[nd.x * SPB] - __int_as_float(nd.y)) > 0.0f);
        }
#pragma unroll
        for (int j = 0; j < 8; ++j) {          // level 4: node in 15..30
            const int lb = (wid + 8 * j) * MID_DW;
            const int2 nd = *reinterpret_cast<const int2*>(
                &mbuf[lb + 2 * node[j] - 14]);
            node[j] = 2 * node[j] + 1 +
                      (int)((xs[nd.x * SPB] - __int_as_float(nd.y)) > 0.0f);
        }
#pragma unroll
        for (int j = 0; j < 8; ++j) {          // level 5: split f/c arrays
            const int lb = (wid + 8 * j) * MID_DW;
            const int q  = node[j] - 31;
            const int   f = mbuf[lb + 48 + q];
            const float c = __int_as_float(mbuf[lb + 80 + q]);
            node[j] = 2 * node[j] + 1 + (int)((xs[f * SPB] - c) > 0.0f);
        }
#pragma unroll
        for (int j = 0; j < 8; ++j)            // leaf: node in 63..126
            acc += lbuf[(wid + 8 * j) * 64 + node[j] - 63];

        __syncthreads();   // stage(t+1) landed; walkers done with buf[t&1]
    }

    partials[wid * SPB + s] = acc;
    __syncthreads();
    if (tid < SPB && sbase + tid < B) {
        float r = 0.0f;
#pragma unroll
        for (int l = 0; l < TLANES; ++l) r += partials[l * SPB + tid];
        atomicAdd(&out[sbase + tid], r);   // 2 adds/elem; ulp noise << 2.7 thr
    }
}

// correctness insurance if ws is ever too small (not expected).
__global__ void xgb_naive_kernel(const float* __restrict__ x,
                                 const int*   __restrict__ split_idx,
                                 const float* __restrict__ split_cond,
                                 const float* __restrict__ base_score,
                                 float* __restrict__ out, int B)
{
    const int sI = blockIdx.x * 256 + threadIdx.x;
    if (sI >= B) return;
    float acc = base_score[0];
    for (int t = 0; t < NTREES; ++t) {
        int node = 0;
        for (int d = 0; d < 6; ++d) {
            const int g = t * NNODES + node;
            const float xv = x[(size_t)sI * NFEAT + split_idx[g]];
            node = 2 * node + 1 + (int)((xv - split_cond[g]) > 0.0f);
        }
        acc += split_cond[t * NNODES + node];
    }
    out[sI] = acc;
}

extern "C" void kernel_launch(void* const* d_in, const int* in_sizes, int n_in,
                              void* d_out, int out_size, void* d_ws, size_t ws_size,
                              hipStream_t stream)
{
    const float* x          = (const float*)d_in[0];
    const int*   split_idx  = (const int*)d_in[1];
    const float* split_cond = (const float*)d_in[2];
    const float* base_score = (const float*)d_in[3];
    float*       out        = (float*)d_out;

    const int B = out_size;                               // 50000

    if (ws_size < (size_t)WS_NEED) {
        xgb_naive_kernel<<<(B + 255) / 256, 256, 0, stream>>>(
            x, split_idx, split_cond, base_score, out, B);
        return;
    }

    xgb_init_kernel<<<(B + 255) / 256, 256, 0, stream>>>(base_score, out, B);

    xgb_pack_kernel<<<(TPAD * NNODES + 255) / 256, 256, 0, stream>>>(
        split_idx, split_cond, (char*)d_ws);

    const int grid = ((B + SPB - 1) / SPB) * NSPLIT;      // 1564
    xgb_forest_kernel<<<grid, NTH, 0, stream>>>(x, (const char*)d_ws, out, B);
}

// Round 7
// 134.322 us; speedup vs baseline: 1.6851x; 1.6851x over previous
//
#include <hip/hip_runtime.h>
#include <stdint.h>

// XGBoost forest inference: B=50000, F=256, T=1000, depth=6, 127 nodes/tree.
// v7: consolidate the validated model. All-LDS walk for levels 0-5 (proven
// 8cy b64 tree read + 5.8cy gather per level; conflict-free layout), leaf
// from GLOBAL (chain-independent: latency amortizes per tile; 4-line TA on
// the idle VMEM pipe -- NOT in the dependent chain, unlike v2/v4's levels).
// Tree tiles staged via global_load_lds (no reg-staging tax), double-
// buffered mids, one barrier per tile. Makespan: 782 sample-tiles =
// 768 full blocks (3 clean rounds of 256) + 14 leftover tiles sliced into
// 16 tree-slice blocks each (tail ~4% of a round) combined via atomicAdd.
// Lessons kept: no divergent VMEM in the walk chain (v2/v4/v5), no scalar
// loads in the walk (v3), no register-cached tops (v6 codegen failure).

#define NFEAT   256
#define NNODES  127
#define NTREES  1000
#define TPAD    1024
#define SPB     64       // samples per block (= lanes per wave)
#define NTH     512      // 8 waves
#define TILE_T  64       // trees per tile; 8 trees per wave per tile
#define MID_DW  128      // dwords per tree record: node n (0..62) int2 at dw 2n
#define NTILES  16       // full block walks 1024 padded trees
#define FULLB   768      // full-tile blocks (sample tiles 0..767)
#define LEFT    14       // leftover sample tiles 768..781, tree-sliced
#define SLICES  16       // slices per leftover tile (64 padded trees each)

#define MID_OFF  0                       // int [TPAD][128] = 512 KB
#define LEAF_OFF (TPAD * 512)            // float[TPAD][64] = 256 KB
#define WS_NEED  (TPAD * 512 + TPAD * 256)

typedef __attribute__((address_space(1))) const unsigned char ga_u8;
typedef __attribute__((address_space(3))) unsigned char       la_u8;

__global__ void xgb_init_kernel(const float* __restrict__ base_score,
                                float* __restrict__ out, int B)
{
    const int i = blockIdx.x * 256 + threadIdx.x;
    if (i < B) out[i] = base_score[0];
}

// pack into d_ws; trees >= NTREES are zero dummies (leaf 0 -> contribute 0).
__global__ void xgb_pack_kernel(const int* __restrict__ idx,
                                const float* __restrict__ cond,
                                char* __restrict__ ws)
{
    const int i = blockIdx.x * 256 + threadIdx.x;
    if (i >= TPAD * NNODES) return;
    const int t  = i / NNODES;
    const int nd = i - t * NNODES;
    int   f = 0;
    float c = 0.0f;
    if (t < NTREES) { f = idx[i]; c = cond[i]; }
    if (nd < 63) {
        int* mid = (int*)(ws + MID_OFF) + (size_t)t * MID_DW;
        mid[2 * nd]     = f;
        mid[2 * nd + 1] = __float_as_int(c);
    } else {
        ((float*)(ws + LEAF_OFF))[t * 64 + (nd - 63)] = c;
    }
}

// stage one 64-tree mid tile (32 KB = 32 chunks of 1KB) via global_load_lds.
// chunk index c wave-uniform; lane offset on the GLOBAL side only (linear
// LDS dest = uniform base + lane*16, per the HW contract).
__device__ __forceinline__ void stage_mid(const char* __restrict__ midG,
                                          int tileIdx, char* dst,
                                          int wid, int lane)
{
    const char* src = midG + (size_t)tileIdx * (TILE_T * 512);
    for (int c = wid; c < 32; c += 8) {
        const char* g = src + c * 1024 + lane * 16;
        char*       l = dst + c * 1024;
#if __has_builtin(__builtin_amdgcn_global_load_lds)
        __builtin_amdgcn_global_load_lds((ga_u8*)(uintptr_t)g,
                                         (la_u8*)(uintptr_t)l, 16, 0, 0);
#else
        *reinterpret_cast<int4*>(l + lane * 16) =
            *reinterpret_cast<const int4*>(g);
#endif
    }
}

__global__ __launch_bounds__(NTH, 1) void xgb_forest_kernel(
    const float* __restrict__ x,
    const char*  __restrict__ ws,
    const float* __restrict__ base_score,
    float* __restrict__ out, int B)
{
    __shared__ float xT[NFEAT * SPB];                       // 64 KB
    __shared__ __align__(16) int midL[2][TILE_T * MID_DW];  // 64 KB
    __shared__ float partials[8 * SPB];                     //  2 KB

    const char*  midG  = ws + MID_OFF;
    const float* leafG = (const float*)(ws + LEAF_OFF);

    const int tid = threadIdx.x;
    const int bid = blockIdx.x;
    const int s   = tid & 63;
    const int wid = tid >> 6;

    // block role: full tile (16 tree-tiles) or one tree-slice of a leftover
    int sTile, tTile0, nTiles;
    if (bid < FULLB) {
        sTile = bid;            tTile0 = 0;        nTiles = NTILES;
    } else {
        const int u = bid - FULLB;                 // 0..223
        sTile = FULLB + (u >> 4); tTile0 = u & 15; nTiles = 1;
    }
    const int sbase = sTile * SPB;

    // prologue: stage first (two) mid tiles; overlaps with x-staging
    stage_mid(midG, tTile0, (char*)midL[0], wid, s);
    if (nTiles > 1) stage_mid(midG, tTile0 + 1, (char*)midL[1], wid, s);

    // ---- stage x tile, transposed (gather bank = sample%32, conflict-free)
    {
        const int sq = tid & 15;
        const int cg = tid >> 4;               // 0..31
        for (int rg = 0; rg < 4; ++rg) {
            const int  sl = rg * 16 + sq;
            const bool ok = (sbase + sl) < B;
            for (int ci = 0; ci < 2; ++ci) {
                const int c4 = ci * 32 + cg;
                float4 v = make_float4(0.f, 0.f, 0.f, 0.f);
                if (ok)
                    v = *reinterpret_cast<const float4*>(
                        &x[(size_t)(sbase + sl) * NFEAT + c4 * 4]);
                xT[(c4 * 4 + 0) * SPB + sl] = v.x;
                xT[(c4 * 4 + 1) * SPB + sl] = v.y;
                xT[(c4 * 4 + 2) * SPB + sl] = v.z;
                xT[(c4 * 4 + 3) * SPB + sl] = v.w;
            }
        }
    }
    __syncthreads();   // xT ready; staged tiles landed (vmcnt drained)

    const float* xs = &xT[s];
    float acc = 0.0f;

    for (int t = 0; t < nTiles; ++t) {
        const int* mbuf = midL[t & 1];
        const int  tgB  = (tTile0 + t) * TILE_T + wid * 8;  // padded tree base
        const int  lb   = wid * 8 * MID_DW;

        int node[8];
#pragma unroll
        for (int j = 0; j < 8; ++j) node[j] = 0;

        // levels 0-5: all-LDS, conflict-free (node n at dw 2n: every level's
        // candidate set maps to distinct banks or 2-way-distinct = free)
#pragma unroll
        for (int d = 0; d < 6; ++d) {
#pragma unroll
            for (int j = 0; j < 8; ++j) {
                const int2 nd = *reinterpret_cast<const int2*>(
                    &mbuf[lb + j * MID_DW + 2 * node[j]]);
                const float xv = xs[nd.x * SPB];
                node[j] = 2 * node[j] + 1 +
                          (int)((xv - __int_as_float(nd.y)) > 0.0f);
            }
        }

        // leaf: global (L2-resident, 256B/tree = 4 lines; chain-independent,
        // latency amortized per tile on the otherwise-idle VMEM pipe)
#pragma unroll
        for (int j = 0; j < 8; ++j)
            acc += leafG[(size_t)(tgB + j) * 64 + (node[j] - 63)];

        __syncthreads();   // all waves done with mbuf; in-flight stage landed
        if (t + 2 < nTiles)
            stage_mid(midG, tTile0 + t + 2, (char*)midL[t & 1], wid, s);
    }

    partials[wid * SPB + s] = acc;
    __syncthreads();
    if (tid < SPB && sbase + tid < B) {
        float r = 0.0f;
#pragma unroll
        for (int l = 0; l < 8; ++l) r += partials[l * SPB + tid];
        if (bid < FULLB) out[sbase + tid] = r + base_score[0];
        else             atomicAdd(&out[sbase + tid], r);  // ulp noise << 2.7
    }
}

// correctness insurance if ws is ever too small (not expected).
__global__ void xgb_naive_kernel(const float* __restrict__ x,
                                 const int*   __restrict__ split_idx,
                                 const float* __restrict__ split_cond,
                                 const float* __restrict__ base_score,
                                 float* __restrict__ out, int B)
{
    const int sI = blockIdx.x * 256 + threadIdx.x;
    if (sI >= B) return;
    float acc = base_score[0];
    for (int t = 0; t < NTREES; ++t) {
        int node = 0;
        for (int d = 0; d < 6; ++d) {
            const int g = t * NNODES + node;
            const float xv = x[(size_t)sI * NFEAT + split_idx[g]];
            node = 2 * node + 1 + (int)((xv - split_cond[g]) > 0.0f);
        }
        acc += split_cond[t * NNODES + node];
    }
    out[sI] = acc;
}

extern "C" void kernel_launch(void* const* d_in, const int* in_sizes, int n_in,
                              void* d_out, int out_size, void* d_ws, size_t ws_size,
                              hipStream_t stream)
{
    const float* x          = (const float*)d_in[0];
    const int*   split_idx  = (const int*)d_in[1];
    const float* split_cond = (const float*)d_in[2];
    const float* base_score = (const float*)d_in[3];
    float*       out        = (float*)d_out;

    const int B = out_size;                               // 50000

    if (ws_size < (size_t)WS_NEED) {
        xgb_naive_kernel<<<(B + 255) / 256, 256, 0, stream>>>(
            x, split_idx, split_cond, base_score, out, B);
        return;
    }

    xgb_init_kernel<<<(B + 255) / 256, 256, 0, stream>>>(base_score, out, B);

    xgb_pack_kernel<<<(TPAD * NNODES + 255) / 256, 256, 0, stream>>>(
        split_idx, split_cond, (char*)d_ws);

    const int grid = FULLB + LEFT * SLICES;               // 992
    xgb_forest_kernel<<<grid, NTH, 0, stream>>>(
        x, (const char*)d_ws, base_score, out, B);
}

// Round 8
// 116.483 us; speedup vs baseline: 1.9432x; 1.1531x over previous
//
#include <hip/hip_runtime.h>
#include <stdint.h>

// XGBoost forest inference: B=50000, F=256, T=1000, depth=6, 127 nodes/tree.
// v8 = v7 (validated: all-LDS walk 83cy/visit, leaf off-chain via global,
// 768 full blocks + 14x16 tree-slice tail) minus the 16 per-tile barriers:
// tree staging is PER-WAVE (global_load_lds is a per-wave DMA; each wave
// stages its own 8 trees = 4KB into its own double-buffered LDS region),
// so the inter-tile dep is wave-local and enforced by one
// `s_waitcnt vmcnt(4)` per tile (allow just-issued stage(t+2) in flight,
// drain stage(t+1) and older -- issued ~6500cy earlier, wait is ~free).
// Barriers: 2 per block (xT ready, final reduction) instead of 17.
// Lessons kept: no divergent VMEM in the walk chain (v2/v4/v5), no scalar
// loads in the walk (v3), no register-cached tops (v6), leaf loads are
// chain-independent so their VMEM latency amortizes (v7).

#define NFEAT   256
#define NNODES  127
#define NTREES  1000
#define TPAD    1024
#define SPB     64       // samples per block (= lanes per wave)
#define NTH     512      // 8 waves
#define TILE_T  64       // trees per tile; 8 per wave
#define TPW     8        // trees per wave per tile
#define MID_DW  128      // dwords per tree record: node n (0..62) int2 at dw 2n
#define NTILES  16       // full block walks 1024 padded trees
#define FULLB   768      // full-tile blocks (sample tiles 0..767)
#define LEFT    14       // leftover sample tiles 768..781, tree-sliced
#define SLICES  16

#define MID_OFF  0                       // int [TPAD][128] = 512 KB
#define LEAF_OFF (TPAD * 512)            // float[TPAD][64] = 256 KB
#define WS_NEED  (TPAD * 512 + TPAD * 256)

typedef __attribute__((address_space(1))) const unsigned char ga_u8;
typedef __attribute__((address_space(3))) unsigned char       la_u8;

// pack into d_ws; trees >= NTREES are zero dummies (leaf 0 -> contribute 0).
// Also initializes out[] for the 896 tail samples (tail blocks atomicAdd).
__global__ void xgb_pack_kernel(const int* __restrict__ idx,
                                const float* __restrict__ cond,
                                char* __restrict__ ws,
                                const float* __restrict__ base_score,
                                float* __restrict__ out, int B)
{
    const int i = blockIdx.x * 256 + threadIdx.x;
    if (i < B - FULLB * SPB) out[FULLB * SPB + i] = base_score[0];
    if (i >= TPAD * NNODES) return;
    const int t  = i / NNODES;
    const int nd = i - t * NNODES;
    int   f = 0;
    float c = 0.0f;
    if (t < NTREES) { f = idx[i]; c = cond[i]; }
    if (nd < 63) {
        int* mid = (int*)(ws + MID_OFF) + (size_t)t * MID_DW;
        mid[2 * nd]     = f;
        mid[2 * nd + 1] = __float_as_int(c);
    } else {
        ((float*)(ws + LEAF_OFF))[t * 64 + (nd - 63)] = c;
    }
}

// per-wave stage: this wave's 8 trees of tile tileIdx (4KB = 4 x 1KB chunks)
// into its own LDS buffer. LDS dest = wave-uniform base (+ implicit lane*16);
// global src per-lane. No cross-wave dependency -> no barrier needed.
__device__ __forceinline__ void stage_wave(const char* __restrict__ midG,
                                           int tileIdx, char* dst,
                                           int wid, int lane)
{
    const char* src = midG + ((size_t)tileIdx * TILE_T + wid * TPW) * 512;
#pragma unroll
    for (int c = 0; c < 4; ++c) {
#if __has_builtin(__builtin_amdgcn_global_load_lds)
        __builtin_amdgcn_global_load_lds(
            (ga_u8*)(uintptr_t)(src + c * 1024 + lane * 16),
            (la_u8*)(uintptr_t)(dst + c * 1024), 16, 0, 0);
#else
        *reinterpret_cast<int4*>(dst + c * 1024 + lane * 16) =
            *reinterpret_cast<const int4*>(src + c * 1024 + lane * 16);
#endif
    }
}

__global__ __launch_bounds__(NTH, 1) void xgb_forest_kernel(
    const float* __restrict__ x,
    const char*  __restrict__ ws,
    const float* __restrict__ base_score,
    float* __restrict__ out, int B)
{
    __shared__ float xT[NFEAT * SPB];                         // 64 KB
    __shared__ __align__(16) int midL[8][2][TPW * MID_DW];    // 64 KB
    __shared__ float partials[8 * SPB];                       //  2 KB

    const char*  midG  = ws + MID_OFF;
    const float* leafG = (const float*)(ws + LEAF_OFF);

    const int tid = threadIdx.x;
    const int bid = blockIdx.x;
    const int s   = tid & 63;
    const int wid = tid >> 6;

    // block role: full (16 tree-tiles) or one tree-slice of a leftover tile
    int sTile, tTile0, nTiles;
    if (bid < FULLB) {
        sTile = bid;              tTile0 = 0;        nTiles = NTILES;
    } else {
        const int u = bid - FULLB;                   // 0..223
        sTile = FULLB + (u >> 4); tTile0 = u & 15;   nTiles = 1;
    }
    const int sbase = sTile * SPB;

    // prologue: stage first (two) tiles for THIS wave; flies under x-staging
    stage_wave(midG, tTile0, (char*)midL[wid][0], wid, s);
    if (nTiles > 1) stage_wave(midG, tTile0 + 1, (char*)midL[wid][1], wid, s);

    // ---- stage x tile, transposed (gather bank = sample%32, conflict-free)
    {
        const int sq = tid & 15;
        const int cg = tid >> 4;               // 0..31
        for (int rg = 0; rg < 4; ++rg) {
            const int  sl = rg * 16 + sq;
            const bool ok = (sbase + sl) < B;
            for (int ci = 0; ci < 2; ++ci) {
                const int c4 = ci * 32 + cg;
                float4 v = make_float4(0.f, 0.f, 0.f, 0.f);
                if (ok)
                    v = *reinterpret_cast<const float4*>(
                        &x[(size_t)(sbase + sl) * NFEAT + c4 * 4]);
                xT[(c4 * 4 + 0) * SPB + sl] = v.x;
                xT[(c4 * 4 + 1) * SPB + sl] = v.y;
                xT[(c4 * 4 + 2) * SPB + sl] = v.z;
                xT[(c4 * 4 + 3) * SPB + sl] = v.w;
            }
        }
    }
    __syncthreads();   // xT visible to all waves; drains vmcnt (tiles 0,1 landed)

    const float* xs = &xT[s];
    float acc = 0.0f;

    for (int t = 0; t < nTiles; ++t) {
        const int* mbuf = &midL[wid][t & 1][0];
        const int  tgB  = (tTile0 + t) * TILE_T + wid * TPW;  // padded tree base

        int node[TPW];
#pragma unroll
        for (int j = 0; j < TPW; ++j) node[j] = 0;

        // levels 0-5: all-LDS (b64 tree + b32 gather, conflict-free/2-way)
#pragma unroll
        for (int d = 0; d < 6; ++d) {
#pragma unroll
            for (int j = 0; j < TPW; ++j) {
                const int2 nd = *reinterpret_cast<const int2*>(
                    &mbuf[j * MID_DW + 2 * node[j]]);
                const float xv = xs[nd.x * SPB];
                node[j] = 2 * node[j] + 1 +
                          (int)((xv - __int_as_float(nd.y)) > 0.0f);
            }
        }

        // leaf: global, chain-independent (addresses ready; latency amortizes)
#pragma unroll
        for (int j = 0; j < TPW; ++j)
            acc += leafG[(size_t)(tgB + j) * 64 + (node[j] - 63)];

        // re-stage the buffer just walked with tile t+2 (per-wave DMA)
        if (t + 2 < nTiles)
            stage_wave(midG, tTile0 + t + 2, (char*)midL[wid][t & 1], wid, s);

        // wave-local pipeline fence: stage(t+1) (and older) complete; allow
        // the 4 just-issued stage(t+2) ops to remain in flight.
        asm volatile("s_waitcnt vmcnt(4)" ::: "memory");
    }

    partials[wid * SPB + s] = acc;
    __syncthreads();
    if (tid < SPB && sbase + tid < B) {
        float r = 0.0f;
#pragma unroll
        for (int l = 0; l < 8; ++l) r += partials[l * SPB + tid];
        if (bid < FULLB) out[sbase + tid] = r + base_score[0];
        else             atomicAdd(&out[sbase + tid], r);  // ulp noise << 2.7
    }
}

// correctness insurance if ws is ever too small (not expected).
__global__ void xgb_naive_kernel(const float* __restrict__ x,
                                 const int*   __restrict__ split_idx,
                                 const float* __restrict__ split_cond,
                                 const float* __restrict__ base_score,
                                 float* __restrict__ out, int B)
{
    const int sI = blockIdx.x * 256 + threadIdx.x;
    if (sI >= B) return;
    float acc = base_score[0];
    for (int t = 0; t < NTREES; ++t) {
        int node = 0;
        for (int d = 0; d < 6; ++d) {
            const int g = t * NNODES + node;
            const float xv = x[(size_t)sI * NFEAT + split_idx[g]];
            node = 2 * node + 1 + (int)((xv - split_cond[g]) > 0.0f);
        }
        acc += split_cond[t * NNODES + node];
    }
    out[sI] = acc;
}

extern "C" void kernel_launch(void* const* d_in, const int* in_sizes, int n_in,
                              void* d_out, int out_size, void* d_ws, size_t ws_size,
                              hipStream_t stream)
{
    const float* x          = (const float*)d_in[0];
    const int*   split_idx  = (const int*)d_in[1];
    const float* split_cond = (const float*)d_in[2];
    const float* base_score = (const float*)d_in[3];
    float*       out        = (float*)d_out;

    const int B = out_size;                               // 50000

    if (ws_size < (size_t)WS_NEED) {
        xgb_naive_kernel<<<(B + 255) / 256, 256, 0, stream>>>(
            x, split_idx, split_cond, base_score, out, B);
        return;
    }

    xgb_pack_kernel<<<(TPAD * NNODES + 255) / 256, 256, 0, stream>>>(
        split_idx, split_cond, (char*)d_ws, base_score, out, B);

    const int grid = FULLB + LEFT * SLICES;               // 992
    xgb_forest_kernel<<<grid, NTH, 0, stream>>>(
        x, (const char*)d_ws, base_score, out, B);
}